// Round 8
// baseline (1510.054 us; speedup 1.0000x reference)
//
#include <hip/hip_runtime.h>
#include <hip/hip_cooperative_groups.h>

namespace cg = cooperative_groups;

#define LEAKY(x) ((x) > 0.0f ? (x) : 0.01f * (x))

typedef __attribute__((ext_vector_type(8))) short bf16x8;      // MFMA A/B frag
typedef __attribute__((ext_vector_type(4))) float f32x4;       // MFMA C/D frag
typedef __attribute__((ext_vector_type(8))) unsigned short u16x8;
typedef __attribute__((ext_vector_type(4))) unsigned short u16x4;

__device__ __forceinline__ unsigned short f2bf(float f) {
    unsigned int u = __float_as_uint(f);
    unsigned int r = (u + 0x7fffu + ((u >> 16) & 1u)) >> 16;   // RNE
    return (unsigned short)r;
}
__device__ __forceinline__ float bf2f(unsigned short u) {
    return __uint_as_float(((unsigned int)u) << 16);
}

#define GLD16(gp, lp) __builtin_amdgcn_global_load_lds( \
    (__attribute__((address_space(1))) void*)(gp), \
    (__attribute__((address_space(3))) void*)(lp), 16, 0, 0)

struct MegaArgs {
    const float *loc, *deadline, *depot, *Wi, *bi, *Wd, *bd;
    const float *Wg1, *Wg2, *Wg3, *bg1, *bg2, *bg3, *gamma, *beta, *WF, *bF;
    float *out, *ws;
};

// ws layout (float offsets)
__device__ __forceinline__ void ws_ptrs(float* ws,
    float*& dmaxv, float*& pmax64, float*& bn1, float*& bn2, float*& msum,
    float*& rowsum, float*& beffv,
    unsigned short*& Lb, unsigned short*& P1, unsigned short*& P2, unsigned short*& P3,
    unsigned short*& WgT, unsigned short*& WFsT, unsigned short*& Y2T,
    unsigned short*& ZT, unsigned short*& F1b)
{
    dmaxv  = ws + 0;
    pmax64 = ws + 4;
    bn1    = ws + 68;
    bn2    = ws + 452;
    msum   = ws + 836;
    rowsum = ws + 4932;
    beffv  = ws + 21316;
    Lb   = (unsigned short*)(ws + 21448);
    P1   = (unsigned short*)(ws + 4215752);
    P2   = (unsigned short*)(ws + 7361480);
    P3   = (unsigned short*)(ws + 10507208);
    WgT  = (unsigned short*)(ws + 13652936);
    WFsT = (unsigned short*)(ws + 13874120);
    Y2T  = (unsigned short*)(ws + 13898696);
    ZT   = (unsigned short*)(ws + 17044424);
    F1b  = (unsigned short*)(ws + 20190152);
}

// ---------------- pipelined MFMA cores (r6 bodies, verified) ----------------

template <bool SWAP>
__device__ __forceinline__ void pipe128x64(
    const unsigned short* __restrict__ A0, int As0, const unsigned short* __restrict__ B0, int Bs0, int it0,
    const unsigned short* __restrict__ A1, int As1, const unsigned short* __restrict__ B1, int Bs1, int it1,
    unsigned short* AsL, unsigned short* BsL,   // A: 2x8192 u16, B: 2x4096 u16
    f32x4 (&acc)[4][2], int t)
{
    const int lane = t & 63, wave = t >> 6;
    const int wm = wave >> 1, wn = wave & 1;
    const int quad = lane >> 4, l16 = lane & 15;
    const int lrow = lane >> 3;
    const int lsw  = ((lane & 7) ^ lrow) * 8;
    const int total = it0 + it1;

    auto stage = [&](int buf, int s) {           // 6 DMA instr / wave / tile
        int sg = (s >= it0);
        const unsigned short* A = sg ? A1 : A0;
        const unsigned short* B = sg ? B1 : B0;
        int As = sg ? As1 : As0, Bs = sg ? Bs1 : Bs0;
        int k0 = (sg ? (s - it0) : s) * 64;
#pragma unroll
        for (int j = 0; j < 4; j++) {
            int r0 = wave * 32 + j * 8;
            GLD16(A + (size_t)(r0 + lrow) * As + k0 + lsw, AsL + buf * 8192 + r0 * 64);
        }
#pragma unroll
        for (int j = 0; j < 2; j++) {
            int r0 = wave * 16 + j * 8;
            GLD16(B + (size_t)(r0 + lrow) * Bs + k0 + lsw, BsL + buf * 4096 + r0 * 64);
        }
    };

    stage(0, 0);
    if (total > 1) stage(1, 1);
    for (int s = 0; s < total; s++) {
        const int buf = s & 1;
        if (s + 1 < total) asm volatile("s_waitcnt vmcnt(6)" ::: "memory");
        else               asm volatile("s_waitcnt vmcnt(0)" ::: "memory");
        __builtin_amdgcn_s_barrier();
        __builtin_amdgcn_sched_barrier(0);
        bf16x8 af[2][4], bfr[2][2];
#pragma unroll
        for (int h = 0; h < 2; h++) {
            int phys = ((h * 4 + quad) ^ (l16 & 7)) * 8;
#pragma unroll
            for (int i = 0; i < 4; i++)
                af[h][i] = *(const bf16x8*)(AsL + buf * 8192 + (wm * 64 + i * 16 + l16) * 64 + phys);
#pragma unroll
            for (int n = 0; n < 2; n++)
                bfr[h][n] = *(const bf16x8*)(BsL + buf * 4096 + (wn * 32 + n * 16 + l16) * 64 + phys);
        }
        asm volatile("s_waitcnt lgkmcnt(0)" ::: "memory");
        __builtin_amdgcn_sched_barrier(0);
        __builtin_amdgcn_s_barrier();
        __builtin_amdgcn_sched_barrier(0);
        if (s + 2 < total) stage(buf, s + 2);
#pragma unroll
        for (int h = 0; h < 2; h++)
#pragma unroll
            for (int i = 0; i < 4; i++)
#pragma unroll
                for (int n = 0; n < 2; n++)
                    acc[i][n] = SWAP
                        ? __builtin_amdgcn_mfma_f32_16x16x32_bf16(bfr[h][n], af[h][i], acc[i][n], 0, 0, 0)
                        : __builtin_amdgcn_mfma_f32_16x16x32_bf16(af[h][i], bfr[h][n], acc[i][n], 0, 0, 0);
    }
}

__device__ __forceinline__ void pipe64x64(
    const unsigned short* __restrict__ A0, int As0, const unsigned short* __restrict__ B0, int Bs0, int it0,
    unsigned short* AsL, unsigned short* BsL,   // 2x4096 / 2x4096 u16
    f32x4 (&acc)[2][2], int t)
{
    const int lane = t & 63, wave = t >> 6;
    const int wm = wave >> 1, wn = wave & 1;
    const int quad = lane >> 4, l16 = lane & 15;
    const int lrow = lane >> 3;
    const int lsw  = ((lane & 7) ^ lrow) * 8;

    auto stage = [&](int buf, int s) {
        int k0 = s * 64;
#pragma unroll
        for (int j = 0; j < 2; j++) {
            int r0 = wave * 16 + j * 8;
            GLD16(A0 + (size_t)(r0 + lrow) * As0 + k0 + lsw, AsL + buf * 4096 + r0 * 64);
            GLD16(B0 + (size_t)(r0 + lrow) * Bs0 + k0 + lsw, BsL + buf * 4096 + r0 * 64);
        }
    };

    stage(0, 0);
    if (it0 > 1) stage(1, 1);
    for (int s = 0; s < it0; s++) {
        const int buf = s & 1;
        if (s + 1 < it0) asm volatile("s_waitcnt vmcnt(4)" ::: "memory");
        else             asm volatile("s_waitcnt vmcnt(0)" ::: "memory");
        __builtin_amdgcn_s_barrier();
        __builtin_amdgcn_sched_barrier(0);
        bf16x8 af[2][2], bfr[2][2];
#pragma unroll
        for (int h = 0; h < 2; h++) {
            int phys = ((h * 4 + quad) ^ (l16 & 7)) * 8;
#pragma unroll
            for (int i = 0; i < 2; i++)
                af[h][i] = *(const bf16x8*)(AsL + buf * 4096 + (wm * 32 + i * 16 + l16) * 64 + phys);
#pragma unroll
            for (int n = 0; n < 2; n++)
                bfr[h][n] = *(const bf16x8*)(BsL + buf * 4096 + (wn * 32 + n * 16 + l16) * 64 + phys);
        }
        asm volatile("s_waitcnt lgkmcnt(0)" ::: "memory");
        __builtin_amdgcn_sched_barrier(0);
        __builtin_amdgcn_s_barrier();
        __builtin_amdgcn_sched_barrier(0);
        if (s + 2 < it0) stage(buf, s + 2);
#pragma unroll
        for (int h = 0; h < 2; h++)
#pragma unroll
            for (int i = 0; i < 2; i++)
#pragma unroll
                for (int n = 0; n < 2; n++)
                    acc[i][n] = __builtin_amdgcn_mfma_f32_16x16x32_bf16(af[h][i], bfr[h][n], acc[i][n], 0, 0, 0);
    }
}

// ---------------- phase bodies ----------------

__device__ __forceinline__ void ph_dmax(const MegaArgs& a, int blk, float* fsh) {
    float *dmaxv, *pmax64, *bn1, *bn2, *msum, *rowsum, *beffv;
    unsigned short *Lb, *P1, *P2, *P3, *WgT, *WFsT, *Y2T, *ZT, *F1b;
    ws_ptrs(a.ws, dmaxv, pmax64, bn1, bn2, msum, rowsum, beffv, Lb, P1, P2, P3, WgT, WFsT, Y2T, ZT, F1b);
    int t = threadIdx.x;
    float m = a.deadline[blk * 256 + t];
    for (int off = 32; off > 0; off >>= 1) m = fmaxf(m, __shfl_down(m, off));
    float* s = fsh + 128;
    if ((t & 63) == 0) s[t >> 6] = m;
    __syncthreads();
    if (t == 0) atomicMax((unsigned int*)dmaxv,
                          __float_as_uint(fmaxf(fmaxf(s[0], s[1]), fmaxf(s[2], s[3]))));
    __syncthreads();
}

__device__ __forceinline__ void ph_rowstats(const MegaArgs& a, int blk, float* fsh) {
    float *dmaxv, *pmax64, *bn1, *bn2, *msum, *rowsum, *beffv;
    unsigned short *Lb, *P1, *P2, *P3, *WgT, *WFsT, *Y2T, *ZT, *F1b;
    ws_ptrs(a.ws, dmaxv, pmax64, bn1, bn2, msum, rowsum, beffv, Lb, P1, P2, P3, WgT, WFsT, Y2T, ZT, F1b);
    int wave = threadIdx.x >> 6, lane = threadIdx.x & 63;
    int bi = blk * 4 + wave;
    int b = bi >> 9, i = bi & 511;
    float invd = 1.0f / (*dmaxv);
    const float* lb = a.loc + b * 1024;
    const float* db = a.deadline + b * 512;
    float xi = lb[i * 2], yi = lb[i * 2 + 1], zi = db[i] * invd;
    float lsum = 0.f, lmax = 0.f;
    for (int j = lane; j < 512; j += 64) {
        float d0 = xi - lb[j * 2], d1 = yi - lb[j * 2 + 1], d2 = zi - db[j] * invd;
        float dd = d0 * d0 + d1 * d1 + d2 * d2;
        float r = (j == i) ? 0.f : rsqrtf(dd);
        lsum += r; lmax = fmaxf(lmax, r);
    }
    for (int off = 32; off > 0; off >>= 1) {
        lsum += __shfl_down(lsum, off);
        lmax = fmaxf(lmax, __shfl_down(lmax, off));
    }
    float* smax = fsh + 128;
    if (lane == 0) { rowsum[bi] = lsum; smax[wave] = lmax; }
    __syncthreads();
    if (threadIdx.x == 0) {
        float m = fmaxf(fmaxf(smax[0], smax[1]), fmaxf(smax[2], smax[3]));
        atomicMax((unsigned int*)(pmax64 + (blk & 63)), __float_as_uint(m));
    }
    __syncthreads();
}

__device__ __forceinline__ void ph_build(const MegaArgs& a, int blk, float* fsh) {
    float *dmaxv, *pmax64, *bn1, *bn2, *msum, *rowsum, *beffv;
    unsigned short *Lb, *P1, *P2, *P3, *WgT, *WFsT, *Y2T, *ZT, *F1b;
    ws_ptrs(a.ws, dmaxv, pmax64, bn1, bn2, msum, rowsum, beffv, Lb, P1, P2, P3, WgT, WFsT, Y2T, ZT, F1b);
    int t = threadIdx.x;
    if (blk < 8192) {
        float* amaxS = fsh + 132;
        if (t < 64) {
            float m = pmax64[t];
            for (int off = 32; off > 0; off >>= 1) m = fmaxf(m, __shfl_down(m, off));
            if (t == 0) *amaxS = m;
        }
        __syncthreads();
        float inv = 1.0f / (*amaxS);
        float invd = 1.0f / (*dmaxv);
        __syncthreads();
        int id = blk * 256 + t;
        size_t e = (size_t)id * 4;
        size_t bi = e >> 9;
        int b = (int)(bi >> 9);
        int i = (int)(bi & 511);
        int j0 = (int)(e & 511);
        const float* lb = a.loc + b * 1024;
        const float* db = a.deadline + b * 512;
        float xi = lb[i * 2], yi = lb[i * 2 + 1], zi = db[i] * invd;
        float4 l01 = *(const float4*)(lb + j0 * 2);
        float4 l23 = *(const float4*)(lb + j0 * 2 + 4);
        float4 dj = *(const float4*)(db + j0);
        float diag = rowsum[bi] * inv - 1.0f;
        float jx[4] = {l01.x, l01.z, l23.x, l23.z};
        float jy[4] = {l01.y, l01.w, l23.y, l23.w};
        float jz[4] = {dj.x * invd, dj.y * invd, dj.z * invd, dj.w * invd};
        u16x4 o;
#pragma unroll
        for (int j = 0; j < 4; j++) {
            float d0 = xi - jx[j], d1 = yi - jy[j], d2 = zi - jz[j];
            float dd = d0 * d0 + d1 * d1 + d2 * d2;
            float v = (i == j0 + j) ? diag : -rsqrtf(dd) * inv;
            o[j] = f2bf(v);
        }
        *(u16x4*)(Lb + e) = o;
    } else if (blk < 14336) {
        int id = (blk - 8192) * 256 + t;
        int row = id / 96, c4 = (id % 96) * 4;
        float x0 = a.loc[row * 2], x1 = a.loc[row * 2 + 1], x2 = a.deadline[row] / (*dmaxv);
        float4 w0 = *(const float4*)(a.Wi + c4);
        float4 w1 = *(const float4*)(a.Wi + 384 + c4);
        float4 w2 = *(const float4*)(a.Wi + 768 + c4);
        float4 bb = *(const float4*)(a.bi + c4);
        float f[4] = {x0 * w0.x + x1 * w1.x + x2 * w2.x + bb.x,
                      x0 * w0.y + x1 * w1.y + x2 * w2.y + bb.y,
                      x0 * w0.z + x1 * w1.z + x2 * w2.z + bb.z,
                      x0 * w0.w + x1 * w1.w + x2 * w2.w + bb.w};
        u16x4 o1, o2, o3;
#pragma unroll
        for (int j = 0; j < 4; j++) {
            o1[j] = f2bf(f[j]); o2[j] = f2bf(f[j] * f[j]); o3[j] = f2bf(f[j] * f[j] * f[j]);
        }
        size_t e = (size_t)row * 384 + c4;
        *(u16x4*)(P1 + e) = o1; *(u16x4*)(P2 + e) = o2; *(u16x4*)(P3 + e) = o3;
    } else {
        int id = (blk - 14336) * 256 + t;
        int part = id / 147456, rem = id % 147456;
        int g = rem / 384, k = rem % 384;
        int kp = g >> 7, n = g & 127;
        const float* W = (kp == 0) ? a.Wg1 : (kp == 1 ? a.Wg2 : a.Wg3);
        WgT[id] = f2bf(W[(part * 384 + k) * 128 + n]);
    }
}

__device__ __forceinline__ void ph_ygemm(const MegaArgs& a, int id,
                                         unsigned short* AsL, unsigned short* BsL) {
    float *dmaxv, *pmax64, *bn1, *bn2, *msum, *rowsum, *beffv;
    unsigned short *Lb, *P1, *P2, *P3, *WgT, *WFsT, *Y2T, *ZT, *F1b;
    ws_ptrs(a.ws, dmaxv, pmax64, bn1, bn2, msum, rowsum, beffv, Lb, P1, P2, P3, WgT, WFsT, Y2T, ZT, F1b);
    const int t = threadIdx.x;
    const int b = id & 31, tt = id >> 5;
    const int kp = tt >> 3, nb = tt & 7;
    const unsigned short* P = (kp == 0) ? P1 : (kp == 1 ? P2 : P3);
    f32x4 acc[4][2];
#pragma unroll
    for (int i = 0; i < 4; i++)
#pragma unroll
        for (int n = 0; n < 2; n++) acc[i][n] = (f32x4){0.f, 0.f, 0.f, 0.f};
    pipe128x64<true>(WgT + ((size_t)2 * 384 + kp * 128) * 384, 384,
                     P + ((size_t)b * 512 + nb * 64) * 384, 384, 6,
                     nullptr, 0, nullptr, 0, 0, AsL, BsL, acc, t);
    const int wave = t >> 6, lane = t & 63;
    const int wm = wave >> 1, wn = wave & 1;
    const int quad = lane >> 4, l16 = lane & 15;
#pragma unroll
    for (int i = 0; i < 4; i++) {
        int g = kp * 128 + wm * 64 + i * 16 + l16;
#pragma unroll
        for (int n = 0; n < 2; n++) {
            int node = nb * 64 + wn * 32 + n * 16 + quad * 4;
            u16x4 o;
#pragma unroll
            for (int r = 0; r < 4; r++) o[r] = f2bf(acc[i][n][r]);
            *(u16x4*)(Y2T + ((size_t)b * 384 + g) * 512 + node) = o;
        }
    }
}

__device__ __forceinline__ void ph_lg1(const MegaArgs& a, int id,
                                       unsigned short* AsL, unsigned short* BsL) {
    float *dmaxv, *pmax64, *bn1, *bn2, *msum, *rowsum, *beffv;
    unsigned short *Lb, *P1, *P2, *P3, *WgT, *WFsT, *Y2T, *ZT, *F1b;
    ws_ptrs(a.ws, dmaxv, pmax64, bn1, bn2, msum, rowsum, beffv, Lb, P1, P2, P3, WgT, WFsT, Y2T, ZT, F1b);
    const int t = threadIdx.x;
    const int b = id & 31, tt = id >> 5;
    const int kp = tt >> 3, nb = tt & 7;
    const unsigned short* P = (kp == 0) ? P1 : (kp == 1 ? P2 : P3);
    f32x4 acc[4][2];
#pragma unroll
    for (int i = 0; i < 4; i++)
#pragma unroll
        for (int n = 0; n < 2; n++) acc[i][n] = (f32x4){0.f, 0.f, 0.f, 0.f};
    pipe128x64<true>(Y2T + (size_t)b * 196608 + (size_t)kp * 128 * 512, 512,
                     Lb + (size_t)b * 262144 + (size_t)nb * 64 * 512, 512, 8,
                     WgT + ((size_t)1 * 384 + kp * 128) * 384, 384,
                     P + ((size_t)b * 512 + nb * 64) * 384, 384, 6, AsL, BsL, acc, t);
    const int wave = t >> 6, lane = t & 63;
    const int wm = wave >> 1, wn = wave & 1;
    const int quad = lane >> 4, l16 = lane & 15;
#pragma unroll
    for (int i = 0; i < 4; i++) {
        int g = kp * 128 + wm * 64 + i * 16 + l16;
#pragma unroll
        for (int n = 0; n < 2; n++) {
            int node = nb * 64 + wn * 32 + n * 16 + quad * 4;
            u16x4 o;
#pragma unroll
            for (int r = 0; r < 4; r++) o[r] = f2bf(acc[i][n][r]);
            *(u16x4*)(ZT + ((size_t)b * 384 + g) * 512 + node) = o;
        }
    }
}

__device__ __forceinline__ void ph_lg2(const MegaArgs& a, int id,
                                       unsigned short* AsL, unsigned short* BsL, float* fsh) {
    float *dmaxv, *pmax64, *bn1, *bn2, *msum, *rowsum, *beffv;
    unsigned short *Lb, *P1, *P2, *P3, *WgT, *WFsT, *Y2T, *ZT, *F1b;
    ws_ptrs(a.ws, dmaxv, pmax64, bn1, bn2, msum, rowsum, beffv, Lb, P1, P2, P3, WgT, WFsT, Y2T, ZT, F1b);
    float* bnS = fsh; float* bnQ = fsh + 64;
    const int t = threadIdx.x;
    const int b = id & 31, tt = id >> 5;
    const int mb = tt & 3, gt = tt >> 2;
    const int kp = gt >> 1;
    if (t < 64) { bnS[t] = 0.f; bnQ[t] = 0.f; }
    const unsigned short* P = (kp == 0) ? P1 : (kp == 1 ? P2 : P3);
    f32x4 acc[4][2];
#pragma unroll
    for (int i = 0; i < 4; i++)
#pragma unroll
        for (int n = 0; n < 2; n++) acc[i][n] = (f32x4){0.f, 0.f, 0.f, 0.f};
    pipe128x64<false>(Lb + (size_t)b * 262144 + (size_t)mb * 128 * 512, 512,
                      ZT + (size_t)b * 196608 + (size_t)gt * 64 * 512, 512, 8,
                      P + ((size_t)b * 512 + mb * 128) * 384, 384,
                      WgT + (size_t)(gt * 64) * 384, 384, 6,
                      AsL, BsL, acc, t);
    const int wave = t >> 6, lane = t & 63;
    const int wm = wave >> 1, wn = wave & 1;
    const int quad = lane >> 4, l16 = lane & 15;
    const float* bg = (kp == 0) ? a.bg1 : (kp == 1 ? a.bg2 : a.bg3);
    float ls1[2], ls2[2];
#pragma unroll
    for (int n = 0; n < 2; n++) { ls1[n] = 0.f; ls2[n] = 0.f; }
#pragma unroll
    for (int i = 0; i < 4; i++) {
        int rowl = mb * 128 + wm * 64 + i * 16 + quad * 4;
        size_t rowg = (size_t)b * 512 + rowl;
#pragma unroll
        for (int n = 0; n < 2; n++) {
            int nloc = wn * 32 + n * 16 + l16;
            int g = gt * 64 + nloc;
            float bias = bg[(gt & 1) * 64 + nloc];
#pragma unroll
            for (int r = 0; r < 4; r++) {
                size_t idx = (rowg + r) * 384 + g;
                float c = acc[i][n][r] + bias;
                float v = LEAKY(c) + bf2f(P1[idx]);
                F1b[idx] = f2bf(v);
                ls1[n] += v; ls2[n] += v * v;
            }
        }
    }
#pragma unroll
    for (int n = 0; n < 2; n++) {
        int nloc = wn * 32 + n * 16 + l16;
        atomicAdd(&bnS[nloc], ls1[n]);
        atomicAdd(&bnQ[nloc], ls2[n]);
    }
    __syncthreads();
    if (t < 64) {
        atomicAdd(&bn1[gt * 64 + t], bnS[t]);
        atomicAdd(&bn2[gt * 64 + t], bnQ[t]);
    }
}

__device__ __forceinline__ void ph_bnfold(const MegaArgs& a, int blk, float* ttL) {
    float *dmaxv, *pmax64, *bn1, *bn2, *msum, *rowsum, *beffv;
    unsigned short *Lb, *P1, *P2, *P3, *WgT, *WFsT, *Y2T, *ZT, *F1b;
    ws_ptrs(a.ws, dmaxv, pmax64, bn1, bn2, msum, rowsum, beffv, Lb, P1, P2, P3, WgT, WFsT, Y2T, ZT, F1b);
    if (blk < 192) {
        int id = blk * 256 + threadIdx.x;
        int n = id / 384, k = id % 384;
        float mu = bn1[k] * (1.f / 16384.f);
        float var = bn2[k] * (1.f / 16384.f) - mu * mu;
        float sc = a.gamma[k] / sqrtf(var + 1e-5f);
        WFsT[id] = f2bf(a.WF[k * 128 + n] * sc);
    } else {
        int c = threadIdx.x;
        for (int k = c; k < 384; k += 256) {
            float mu = bn1[k] * (1.f / 16384.f);
            float var = bn2[k] * (1.f / 16384.f) - mu * mu;
            float sc = a.gamma[k] / sqrtf(var + 1e-5f);
            ttL[k] = a.beta[k] - mu * sc;
        }
        __syncthreads();
        if (c < 128) {
            float v = a.bF[c];
            for (int k = 0; k < 384; k++) v += ttL[k] * a.WF[k * 128 + c];
            beffv[c] = v;
        }
    }
}

__device__ __forceinline__ void ph_fgemm(const MegaArgs& a, int id,
                                         unsigned short* AsL, unsigned short* BsL, float* fsh) {
    float *dmaxv, *pmax64, *bn1, *bn2, *msum, *rowsum, *beffv;
    unsigned short *Lb, *P1, *P2, *P3, *WgT, *WFsT, *Y2T, *ZT, *F1b;
    ws_ptrs(a.ws, dmaxv, pmax64, bn1, bn2, msum, rowsum, beffv, Lb, P1, P2, P3, WgT, WFsT, Y2T, ZT, F1b);
    float* msS = fsh;
    const int t = threadIdx.x;
    const int b = id & 31, tt = id >> 5;
    const int seg = tt >> 1, nt = tt & 1;
    if (t < 64) msS[t] = 0.f;
    f32x4 acc[2][2];
#pragma unroll
    for (int i = 0; i < 2; i++)
#pragma unroll
        for (int n = 0; n < 2; n++) acc[i][n] = (f32x4){0.f, 0.f, 0.f, 0.f};
    pipe64x64(F1b + ((size_t)b * 512 + seg * 64) * 384, 384,
              WFsT + (size_t)nt * 64 * 384, 384, 6, AsL, BsL, acc, t);
    const int wave = t >> 6, lane = t & 63;
    const int wm = wave >> 1, wn = wave & 1;
    const int quad = lane >> 4, l16 = lane & 15;
    float ls[2];
#pragma unroll
    for (int n = 0; n < 2; n++) ls[n] = 0.f;
#pragma unroll
    for (int i = 0; i < 2; i++) {
        int nd = seg * 64 + wm * 32 + i * 16 + quad * 4;
#pragma unroll
        for (int n = 0; n < 2; n++) {
            int col = nt * 64 + wn * 32 + n * 16 + l16;
            float bb = beffv[col];
#pragma unroll
            for (int r = 0; r < 4; r++) {
                float x = acc[i][n][r] + bb;
                float v = LEAKY(x);
                a.out[(size_t)b * 65664 + (size_t)(nd + r + 1) * 128 + col] = v;
                ls[n] += v;
            }
        }
    }
#pragma unroll
    for (int n = 0; n < 2; n++) atomicAdd(&msS[wn * 32 + n * 16 + l16], ls[n]);
    __syncthreads();
    if (t < 64) atomicAdd(&msum[b * 128 + nt * 64 + t], msS[t]);
}

__device__ __forceinline__ void ph_meandep(const MegaArgs& a, int id) {
    float *dmaxv, *pmax64, *bn1, *bn2, *msum, *rowsum, *beffv;
    unsigned short *Lb, *P1, *P2, *P3, *WgT, *WFsT, *Y2T, *ZT, *F1b;
    ws_ptrs(a.ws, dmaxv, pmax64, bn1, bn2, msum, rowsum, beffv, Lb, P1, P2, P3, WgT, WFsT, Y2T, ZT, F1b);
    int b = id >> 7, o = id & 127;
    float dep = a.depot[b * 2] * a.Wd[o] + a.depot[b * 2 + 1] * a.Wd[128 + o] + a.bd[o];
    a.out[(size_t)b * 65664 + o] = dep;
    a.out[2101248 + id] = (msum[id] + dep) * (1.0f / 513.0f);
}

// ---------------- mega cooperative kernel: grid 768 x 256t, 3 blocks/CU ----------------

__global__ __launch_bounds__(256, 3) void k_mega(MegaArgs a) {
    cg::grid_group grid = cg::this_grid();
    __shared__ unsigned short AsL[16384];   // 32 KB
    __shared__ unsigned short BsL[8192];    // 16 KB
    __shared__ float fsh[136];              // bnS/bnQ/msS(128) + smax(4) + amaxS
    const int blk = blockIdx.x;

    if (blk < 64) ph_dmax(a, blk, fsh);                 // A
    __threadfence(); grid.sync();
    for (int j = blk; j < 4096; j += 768) ph_rowstats(a, j, fsh);   // B
    __threadfence(); grid.sync();
    for (int j = blk; j < 16064; j += 768) ph_build(a, j, fsh);     // C
    __threadfence(); grid.sync();
    ph_ygemm(a, blk, AsL, BsL);                         // D (768 jobs)
    __threadfence(); grid.sync();
    ph_lg1(a, blk, AsL, BsL);                           // E (768 jobs)
    __threadfence(); grid.sync();
    ph_lg2(a, blk, AsL, BsL, fsh);                      // F (768 jobs)
    __threadfence(); grid.sync();
    if (blk < 193) ph_bnfold(a, blk, (float*)BsL);      // G
    __threadfence(); grid.sync();
    if (blk < 512) ph_fgemm(a, blk, AsL, BsL, fsh);     // H
    __threadfence(); grid.sync();
    if (blk < 16) ph_meandep(a, blk * 256 + threadIdx.x); // I
}

// ---------------- fallback wrappers (multi-kernel path) ----------------

__global__ __launch_bounds__(256) void k_dmax_g(MegaArgs a) {
    __shared__ float fsh[136];
    ph_dmax(a, blockIdx.x, fsh);
}
__global__ __launch_bounds__(256) void k_rowstats_g(MegaArgs a) {
    __shared__ float fsh[136];
    ph_rowstats(a, blockIdx.x, fsh);
}
__global__ __launch_bounds__(256) void k_build_g(MegaArgs a) {
    __shared__ float fsh[136];
    ph_build(a, blockIdx.x, fsh);
}
__global__ __launch_bounds__(256) void k_ygemm_g(MegaArgs a) {
    __shared__ unsigned short AsL[16384], BsL[8192];
    ph_ygemm(a, blockIdx.x, AsL, BsL);
}
__global__ __launch_bounds__(256) void k_lg1_g(MegaArgs a) {
    __shared__ unsigned short AsL[16384], BsL[8192];
    ph_lg1(a, blockIdx.x, AsL, BsL);
}
__global__ __launch_bounds__(256) void k_lg2_g(MegaArgs a) {
    __shared__ unsigned short AsL[16384], BsL[8192];
    __shared__ float fsh[136];
    ph_lg2(a, blockIdx.x, AsL, BsL, fsh);
}
__global__ __launch_bounds__(256) void k_bnfold_g(MegaArgs a) {
    __shared__ float ttL[384];
    ph_bnfold(a, blockIdx.x, ttL);
}
__global__ __launch_bounds__(256) void k_fgemm_g(MegaArgs a) {
    __shared__ unsigned short AsL[16384], BsL[8192];
    __shared__ float fsh[136];
    ph_fgemm(a, blockIdx.x, AsL, BsL, fsh);
}
__global__ __launch_bounds__(256) void k_meandep_g(MegaArgs a) {
    ph_meandep(a, blockIdx.x * 256 + threadIdx.x);
}

// ---------------- launch ----------------

extern "C" void kernel_launch(void* const* d_in, const int* in_sizes, int n_in,
                              void* d_out, int out_size, void* d_ws, size_t ws_size,
                              hipStream_t stream) {
    MegaArgs a;
    a.loc      = (const float*)d_in[0];
    a.deadline = (const float*)d_in[1];
    a.depot    = (const float*)d_in[3];
    a.Wi       = (const float*)d_in[4];
    a.bi       = (const float*)d_in[5];
    a.Wd       = (const float*)d_in[6];
    a.bd       = (const float*)d_in[7];
    a.Wg1      = (const float*)d_in[8];
    a.bg1      = (const float*)d_in[9];
    a.Wg2      = (const float*)d_in[10];
    a.bg2      = (const float*)d_in[11];
    a.Wg3      = (const float*)d_in[12];
    a.bg3      = (const float*)d_in[13];
    a.gamma    = (const float*)d_in[14];
    a.beta     = (const float*)d_in[15];
    a.WF       = (const float*)d_in[16];
    a.bF       = (const float*)d_in[17];
    a.out      = (float*)d_out;
    a.ws       = (float*)d_ws;

    // zero: dmaxv, pmax64, bn1, bn2, msum (contiguous low region)
    hipMemsetAsync(d_ws, 0, 4932 * sizeof(float), stream);

    void* kargs[] = { &a };
    hipError_t err = hipLaunchCooperativeKernel((const void*)k_mega,
                                                dim3(768), dim3(256), kargs, 0, stream);
    if (err != hipSuccess) {
        // fallback: multi-kernel path (identical phase bodies)
        k_dmax_g<<<64, 256, 0, stream>>>(a);
        k_rowstats_g<<<4096, 256, 0, stream>>>(a);
        k_build_g<<<16064, 256, 0, stream>>>(a);
        k_ygemm_g<<<768, 256, 0, stream>>>(a);
        k_lg1_g<<<768, 256, 0, stream>>>(a);
        k_lg2_g<<<768, 256, 0, stream>>>(a);
        k_bnfold_g<<<193, 256, 0, stream>>>(a);
        k_fgemm_g<<<512, 256, 0, stream>>>(a);
        k_meandep_g<<<16, 256, 0, stream>>>(a);
    }
}

// Round 9
// 240.454 us; speedup vs baseline: 6.2800x; 6.2800x over previous
//
#include <hip/hip_runtime.h>

#define LEAKY(x) ((x) > 0.0f ? (x) : 0.01f * (x))

typedef __attribute__((ext_vector_type(8))) short bf16x8;      // MFMA A/B frag
typedef __attribute__((ext_vector_type(4))) float f32x4;       // MFMA C/D frag
typedef __attribute__((ext_vector_type(8))) unsigned short u16x8;
typedef __attribute__((ext_vector_type(4))) unsigned short u16x4;

__device__ __forceinline__ unsigned short f2bf(float f) {
    unsigned int u = __float_as_uint(f);
    unsigned int r = (u + 0x7fffu + ((u >> 16) & 1u)) >> 16;   // RNE
    return (unsigned short)r;
}
__device__ __forceinline__ float bf2f(unsigned short u) {
    return __uint_as_float(((unsigned int)u) << 16);
}

// async global->LDS DMA, 16B per lane. LDS dest is WAVE-UNIFORM base + lane*16;
// global src is per-lane (carries the inverse swizzle).
#define GLD16(gp, lp) __builtin_amdgcn_global_load_lds( \
    (__attribute__((address_space(1))) void*)(gp), \
    (__attribute__((address_space(3))) void*)(lp), 16, 0, 0)

// ---------------- small builds ----------------

// wide max via atomicMax (values > 0 so uint ordering == float ordering); grid 64
__global__ void k_dmax(const float* __restrict__ deadline, float* __restrict__ dmax) {
    int t = threadIdx.x;
    float m = deadline[blockIdx.x * 256 + t];
    for (int off = 32; off > 0; off >>= 1) m = fmaxf(m, __shfl_down(m, off));
    __shared__ float s[4];
    if ((t & 63) == 0) s[t >> 6] = m;
    __syncthreads();
    if (t == 0) atomicMax((unsigned int*)dmax,
                          __float_as_uint(fmaxf(fmaxf(s[0], s[1]), fmaxf(s[2], s[3]))));
}

// rowsum + 64-slot atomicMax partials of r=1/dist; R is NOT materialized
__global__ __launch_bounds__(256) void k_rowstats(const float* __restrict__ loc,
                                                  const float* __restrict__ deadline,
                                                  const float* __restrict__ dmaxv,
                                                  float* __restrict__ rowsum, float* __restrict__ pmax64) {
    int blk = blockIdx.x;                       // 0..4095
    int wave = threadIdx.x >> 6, lane = threadIdx.x & 63;
    int bi = blk * 4 + wave;                    // b*512 + i
    int b = bi >> 9, i = bi & 511;
    float invd = 1.0f / (*dmaxv);
    const float* lb = loc + b * 1024;
    const float* db = deadline + b * 512;
    float xi = lb[i * 2], yi = lb[i * 2 + 1], zi = db[i] * invd;
    float lsum = 0.f, lmax = 0.f;
    for (int j = lane; j < 512; j += 64) {
        float d0 = xi - lb[j * 2], d1 = yi - lb[j * 2 + 1], d2 = zi - db[j] * invd;
        float dd = d0 * d0 + d1 * d1 + d2 * d2;
        float r = (j == i) ? 0.f : rsqrtf(dd);
        lsum += r; lmax = fmaxf(lmax, r);
    }
    for (int off = 32; off > 0; off >>= 1) {
        lsum += __shfl_down(lsum, off);
        lmax = fmaxf(lmax, __shfl_down(lmax, off));
    }
    __shared__ float smax[4];
    if (lane == 0) { rowsum[bi] = lsum; smax[wave] = lmax; }
    __syncthreads();
    if (threadIdx.x == 0) {
        float m = fmaxf(fmaxf(smax[0], smax[1]), fmaxf(smax[2], smax[3]));
        atomicMax((unsigned int*)(pmax64 + (blk & 63)), __float_as_uint(m));
    }
}

// fused build: [0,8192) L ; [8192,14336) F0 powers ; [14336,16064) WgT repack
__global__ __launch_bounds__(256) void k_build(
    const float* __restrict__ loc, const float* __restrict__ deadline,
    const float* __restrict__ dmaxv, const float* __restrict__ rowsum,
    const float* __restrict__ pmax64,
    const float* __restrict__ Wi, const float* __restrict__ bi_,
    const float* __restrict__ Wg1, const float* __restrict__ Wg2, const float* __restrict__ Wg3,
    unsigned short* __restrict__ Lb,
    unsigned short* __restrict__ P1, unsigned short* __restrict__ P2, unsigned short* __restrict__ P3,
    unsigned short* __restrict__ WgT)
{
    __shared__ float amaxS;
    int blk = blockIdx.x;
    int t = threadIdx.x;
    if (blk < 8192) {
        if (t < 64) {
            float m = pmax64[t];
            for (int off = 32; off > 0; off >>= 1) m = fmaxf(m, __shfl_down(m, off));
            if (t == 0) amaxS = m;
        }
        __syncthreads();
        float inv = 1.0f / amaxS;
        float invd = 1.0f / (*dmaxv);
        int id = blk * 256 + t;
        size_t e = (size_t)id * 4;
        size_t bi = e >> 9;
        int b = (int)(bi >> 9);
        int i = (int)(bi & 511);
        int j0 = (int)(e & 511);
        const float* lb = loc + b * 1024;
        const float* db = deadline + b * 512;
        float xi = lb[i * 2], yi = lb[i * 2 + 1], zi = db[i] * invd;
        float4 l01 = *(const float4*)(lb + j0 * 2);
        float4 l23 = *(const float4*)(lb + j0 * 2 + 4);
        float4 dj = *(const float4*)(db + j0);
        float diag = rowsum[bi] * inv - 1.0f;
        float jx[4] = {l01.x, l01.z, l23.x, l23.z};
        float jy[4] = {l01.y, l01.w, l23.y, l23.w};
        float jz[4] = {dj.x * invd, dj.y * invd, dj.z * invd, dj.w * invd};
        u16x4 o;
#pragma unroll
        for (int j = 0; j < 4; j++) {
            float d0 = xi - jx[j], d1 = yi - jy[j], d2 = zi - jz[j];
            float dd = d0 * d0 + d1 * d1 + d2 * d2;
            float v = (i == j0 + j) ? diag : -rsqrtf(dd) * inv;
            o[j] = f2bf(v);
        }
        *(u16x4*)(Lb + e) = o;
    } else if (blk < 14336) {
        int id = (blk - 8192) * 256 + t;          // 1,572,864
        int row = id / 96, c4 = (id % 96) * 4;
        float x0 = loc[row * 2], x1 = loc[row * 2 + 1], x2 = deadline[row] / (*dmaxv);
        float4 w0 = *(const float4*)(Wi + c4);
        float4 w1 = *(const float4*)(Wi + 384 + c4);
        float4 w2 = *(const float4*)(Wi + 768 + c4);
        float4 bb = *(const float4*)(bi_ + c4);
        float f[4] = {x0 * w0.x + x1 * w1.x + x2 * w2.x + bb.x,
                      x0 * w0.y + x1 * w1.y + x2 * w2.y + bb.y,
                      x0 * w0.z + x1 * w1.z + x2 * w2.z + bb.z,
                      x0 * w0.w + x1 * w1.w + x2 * w2.w + bb.w};
        u16x4 o1, o2, o3;
#pragma unroll
        for (int j = 0; j < 4; j++) {
            o1[j] = f2bf(f[j]); o2[j] = f2bf(f[j] * f[j]); o3[j] = f2bf(f[j] * f[j] * f[j]);
        }
        size_t e = (size_t)row * 384 + c4;
        *(u16x4*)(P1 + e) = o1; *(u16x4*)(P2 + e) = o2; *(u16x4*)(P3 + e) = o3;
    } else {
        int id = (blk - 14336) * 256 + t;         // 442368 exact
        int part = id / 147456, rem = id % 147456;
        int g = rem / 384, k = rem % 384;
        int kp = g >> 7, n = g & 127;
        const float* W = (kp == 0) ? Wg1 : (kp == 1 ? Wg2 : Wg3);
        WgT[id] = f2bf(W[(part * 384 + k) * 128 + n]);
    }
}

// ---------------- r3 pipelined MFMA core: counted-vmcnt, 2-deep prefetch ----------------
// grid 384, 128x128, 4 waves 2x2, wave tile 64x64 (4x4 frags), 32 MFMA/iter.
// vmcnt never drains to 0 mid-loop; tile s+1 stays in flight across barriers, tile s+2
// staged under the MFMAs. Swizzle (rule #21): LDS dest linear, global SOURCE pre-swizzled
// per lane with the same involution (chunk ^= row&7) the ds_read side uses.

__device__ __forceinline__ void pipe128x128(
    const unsigned short* __restrict__ A0, int As0, const unsigned short* __restrict__ B0, int Bs0, int it0,
    const unsigned short* __restrict__ A1, int As1, const unsigned short* __restrict__ B1, int Bs1, int it1,
    unsigned short* AsL, unsigned short* BsL,   // each 16384 u16 (2 bufs x 8192)
    f32x4 (&acc)[4][4], int t)
{
    const int lane = t & 63, wave = t >> 6;
    const int wm = wave >> 1, wn = wave & 1;
    const int quad = lane >> 4, l16 = lane & 15;
    const int lrow = lane >> 3;
    const int lsw  = ((lane & 7) ^ lrow) * 8;
    const int total = it0 + it1;

    auto stage = [&](int buf, int s) {           // 8 DMA instr / wave / tile
        int sg = (s >= it0);
        const unsigned short* A = sg ? A1 : A0;
        const unsigned short* B = sg ? B1 : B0;
        int As = sg ? As1 : As0, Bs = sg ? Bs1 : Bs0;
        int k0 = (sg ? (s - it0) : s) * 64;
#pragma unroll
        for (int j = 0; j < 4; j++) {
            int r0 = wave * 32 + j * 8;
            GLD16(A + (size_t)(r0 + lrow) * As + k0 + lsw, AsL + buf * 8192 + r0 * 64);
            GLD16(B + (size_t)(r0 + lrow) * Bs + k0 + lsw, BsL + buf * 8192 + r0 * 64);
        }
    };

    stage(0, 0);
    if (total > 1) stage(1, 1);
    for (int s = 0; s < total; s++) {
        const int buf = s & 1;
        if (s + 1 < total) asm volatile("s_waitcnt vmcnt(8)" ::: "memory");
        else               asm volatile("s_waitcnt vmcnt(0)" ::: "memory");
        __builtin_amdgcn_s_barrier();
        __builtin_amdgcn_sched_barrier(0);
        bf16x8 af[2][4], bfr[2][4];
#pragma unroll
        for (int h = 0; h < 2; h++) {
            int phys = ((h * 4 + quad) ^ (l16 & 7)) * 8;
#pragma unroll
            for (int i = 0; i < 4; i++)
                af[h][i] = *(const bf16x8*)(AsL + buf * 8192 + (wm * 64 + i * 16 + l16) * 64 + phys);
#pragma unroll
            for (int n = 0; n < 4; n++)
                bfr[h][n] = *(const bf16x8*)(BsL + buf * 8192 + (wn * 64 + n * 16 + l16) * 64 + phys);
        }
        asm volatile("s_waitcnt lgkmcnt(0)" ::: "memory");
        __builtin_amdgcn_sched_barrier(0);
        __builtin_amdgcn_s_barrier();
        __builtin_amdgcn_sched_barrier(0);
        if (s + 2 < total) stage(buf, s + 2);
#pragma unroll
        for (int h = 0; h < 2; h++)
#pragma unroll
            for (int i = 0; i < 4; i++)
#pragma unroll
                for (int n = 0; n < 4; n++)
                    acc[i][n] = __builtin_amdgcn_mfma_f32_16x16x32_bf16(af[h][i], bfr[h][n], acc[i][n], 0, 0, 0);
    }
}

// Y2^T[g][node] = WgT(p2)·P^T ; grid 384, id = b + 32*(kp*4+nb)
__global__ __launch_bounds__(256) void k_ygemmT(
    const unsigned short* __restrict__ WgT,
    const unsigned short* __restrict__ P1, const unsigned short* __restrict__ P2,
    const unsigned short* __restrict__ P3, unsigned short* __restrict__ Y2T)
{
    __shared__ unsigned short AsL[16384], BsL[16384];
    const int t = threadIdx.x;
    const int id = blockIdx.x;
    const int b = id & 31, tt = id >> 5;
    const int kp = tt >> 2, nb = tt & 3;
    const unsigned short* P = (kp == 0) ? P1 : (kp == 1 ? P2 : P3);
    f32x4 acc[4][4];
#pragma unroll
    for (int i = 0; i < 4; i++)
#pragma unroll
        for (int n = 0; n < 4; n++) acc[i][n] = (f32x4){0.f, 0.f, 0.f, 0.f};
    pipe128x128(WgT + ((size_t)2 * 384 + kp * 128) * 384, 384,
                P + ((size_t)b * 512 + nb * 128) * 384, 384, 6,
                nullptr, 0, nullptr, 0, 0, AsL, BsL, acc, t);

    const int wave = t >> 6, lane = t & 63;
    const int wm = wave >> 1, wn = wave & 1;
    const int quad = lane >> 4, l16 = lane & 15;
#pragma unroll
    for (int i = 0; i < 4; i++)
#pragma unroll
        for (int n = 0; n < 4; n++) {
            int g = kp * 128 + wm * 64 + i * 16 + quad * 4;
            int node = nb * 128 + wn * 64 + n * 16 + l16;
#pragma unroll
            for (int r = 0; r < 4; r++)
                Y2T[((size_t)b * 384 + g + r) * 512 + node] = f2bf(acc[i][n][r]);
        }
}

// Z^T = Y2T·L + WgT(p1)·P^T ; grid 384
__global__ __launch_bounds__(256) void k_lg1T(
    const unsigned short* __restrict__ Lb, const unsigned short* __restrict__ Y2T,
    const unsigned short* __restrict__ WgT,
    const unsigned short* __restrict__ P1, const unsigned short* __restrict__ P2,
    const unsigned short* __restrict__ P3, unsigned short* __restrict__ ZT)
{
    __shared__ unsigned short AsL[16384], BsL[16384];
    const int t = threadIdx.x;
    const int id = blockIdx.x;
    const int b = id & 31, tt = id >> 5;
    const int kp = tt >> 2, nb = tt & 3;
    const unsigned short* P = (kp == 0) ? P1 : (kp == 1 ? P2 : P3);
    f32x4 acc[4][4];
#pragma unroll
    for (int i = 0; i < 4; i++)
#pragma unroll
        for (int n = 0; n < 4; n++) acc[i][n] = (f32x4){0.f, 0.f, 0.f, 0.f};
    pipe128x128(Y2T + (size_t)b * 196608 + (size_t)kp * 128 * 512, 512,
                Lb + (size_t)b * 262144 + (size_t)nb * 128 * 512, 512, 8,
                WgT + ((size_t)1 * 384 + kp * 128) * 384, 384,
                P + ((size_t)b * 512 + nb * 128) * 384, 384, 6, AsL, BsL, acc, t);

    const int wave = t >> 6, lane = t & 63;
    const int wm = wave >> 1, wn = wave & 1;
    const int quad = lane >> 4, l16 = lane & 15;
#pragma unroll
    for (int i = 0; i < 4; i++)
#pragma unroll
        for (int n = 0; n < 4; n++) {
            int g = kp * 128 + wm * 64 + i * 16 + quad * 4;
            int node = nb * 128 + wn * 64 + n * 16 + l16;
#pragma unroll
            for (int r = 0; r < 4; r++)
                ZT[((size_t)b * 384 + g + r) * 512 + node] = f2bf(acc[i][n][r]);
        }
}

// F1 = leaky(L·Z + P·WgT(p0)^T + bias) + F0 ; fused BN sums ; grid 384, tt = gt*4+mb
__global__ __launch_bounds__(256) void k_lg2(
    const unsigned short* __restrict__ Lb, const unsigned short* __restrict__ ZT,
    const unsigned short* __restrict__ WgT,
    const unsigned short* __restrict__ P1, const unsigned short* __restrict__ P2,
    const unsigned short* __restrict__ P3,
    const float* __restrict__ bg1, const float* __restrict__ bg2, const float* __restrict__ bg3,
    unsigned short* __restrict__ F1b, float* __restrict__ bn1, float* __restrict__ bn2)
{
    __shared__ unsigned short AsL[16384], BsL[16384];
    __shared__ float bnS[128], bnQ[128];
    const int t = threadIdx.x;
    const int id = blockIdx.x;
    const int b = id & 31, tt = id >> 5;
    const int mb = tt & 3, gt = tt >> 2;
    if (t < 128) { bnS[t] = 0.f; bnQ[t] = 0.f; }
    const unsigned short* P = (gt == 0) ? P1 : (gt == 1 ? P2 : P3);
    f32x4 acc[4][4];
#pragma unroll
    for (int i = 0; i < 4; i++)
#pragma unroll
        for (int n = 0; n < 4; n++) acc[i][n] = (f32x4){0.f, 0.f, 0.f, 0.f};
    pipe128x128(Lb + (size_t)b * 262144 + (size_t)mb * 128 * 512, 512,
                ZT + (size_t)b * 196608 + (size_t)gt * 128 * 512, 512, 8,
                P + ((size_t)b * 512 + mb * 128) * 384, 384,
                WgT + (size_t)(gt * 128) * 384, 384, 6,
                AsL, BsL, acc, t);

    const int wave = t >> 6, lane = t & 63;
    const int wm = wave >> 1, wn = wave & 1;
    const int quad = lane >> 4, l16 = lane & 15;
    const float* bg = (gt == 0) ? bg1 : (gt == 1 ? bg2 : bg3);
    float ls1[4], ls2[4];
#pragma unroll
    for (int n = 0; n < 4; n++) { ls1[n] = 0.f; ls2[n] = 0.f; }
#pragma unroll
    for (int i = 0; i < 4; i++) {
        int rowl = mb * 128 + wm * 64 + i * 16 + quad * 4;
        size_t rowg = (size_t)b * 512 + rowl;
#pragma unroll
        for (int n = 0; n < 4; n++) {
            int nloc = wn * 64 + n * 16 + l16;    // 0..127
            int g = gt * 128 + nloc;
            float bias = bg[nloc];
#pragma unroll
            for (int r = 0; r < 4; r++) {
                size_t idx = (rowg + r) * 384 + g;
                float c = acc[i][n][r] + bias;
                float v = LEAKY(c) + bf2f(P1[idx]);   // residual +F0
                F1b[idx] = f2bf(v);
                ls1[n] += v; ls2[n] += v * v;
            }
        }
    }
#pragma unroll
    for (int n = 0; n < 4; n++) {
        int nloc = wn * 64 + n * 16 + l16;
        atomicAdd(&bnS[nloc], ls1[n]);
        atomicAdd(&bnQ[nloc], ls2[n]);
    }
    __syncthreads();
    if (t < 128) {
        atomicAdd(&bn1[gt * 128 + t], bnS[t]);
        atomicAdd(&bn2[gt * 128 + t], bnQ[t]);
    }
}

// ---------------- fused final: fold(BN->W) + GEMM + colsum + last-block meandep ----------------
// grid 512, id = b + 32*(seg*2+nt). Per block: compute its 64x384 folded-W tile into LDS
// (swizzled panels), beff for its 64 cols, then A-only staged MFMA loop, epilogue,
// msum atomics; the 512th block to finish computes the depot row + final means.
__global__ __launch_bounds__(256) void k_fgemm2(
    const unsigned short* __restrict__ F1b,
    const float* __restrict__ bn1, const float* __restrict__ bn2,
    const float* __restrict__ gamma, const float* __restrict__ beta,
    const float* __restrict__ WF, const float* __restrict__ bF,
    const float* __restrict__ depot, const float* __restrict__ Wd, const float* __restrict__ bd,
    float* __restrict__ out, float* __restrict__ msum, unsigned int* __restrict__ donecnt)
{
    __shared__ unsigned short Bs[24576];   // 6 panels x [64 rows][64 k] u16, XOR-swizzled
    __shared__ unsigned short As[8192];    // 2 x 4096 u16 double-buffer
    __shared__ float scS[384], ttS[384];
    __shared__ float beffS[64], beffF[64], msS[64];
    __shared__ unsigned int lastFlag;

    const int t = threadIdx.x;
    const int id = blockIdx.x;
    const int b = id & 31, tt = id >> 5;
    const int seg = tt >> 1, nt = tt & 1;

    // ---- phase 1: BN scale/shift ----
    for (int k = t; k < 384; k += 256) {
        float mu = bn1[k] * (1.f / 16384.f);
        float var = bn2[k] * (1.f / 16384.f) - mu * mu;
        float sc = gamma[k] / sqrtf(var + 1e-5f);
        scS[k] = sc;
        ttS[k] = beta[k] - mu * sc;
    }
    if (t < 64) { beffS[t] = 0.f; msS[t] = 0.f; }
    __syncthreads();

    // ---- phase 2: fold W tile into Bs (row = local col n, swizzled panels) + beff partials ----
    {
        const int row = t & 63;              // local output col
        const int wfc = nt * 64 + row;       // col in WF's 128
        const int kg = t >> 6;               // 0..3, each covers 12 chunks of 8 k
        float bacc = 0.f;
#pragma unroll 4
        for (int j = 0; j < 12; j++) {
            int c = kg * 12 + j;             // chunk 0..47 (8 k each)
            int k0 = c * 8;
            u16x8 pk;
#pragma unroll
            for (int e = 0; e < 8; e++) {
                float w = WF[(size_t)(k0 + e) * 128 + wfc];
                pk[e] = f2bf(w * scS[k0 + e]);
                bacc += ttS[k0 + e] * w;
            }
            *(u16x8*)(Bs + (c >> 3) * 4096 + row * 64 + ((c & 7) ^ (row & 7)) * 8) = pk;
        }
        atomicAdd(&beffS[row], bacc);
    }
    __syncthreads();                          // fold writes + beffS complete
    if (t < 64) beffF[t] = bF[nt * 64 + t] + beffS[t];

    // ---- phase 3: A-staged MFMA loop (B resident in Bs) ----
    const int lane = t & 63, wave = t >> 6;
    const int wm = wave >> 1, wn = wave & 1;
    const int quad = lane >> 4, l16 = lane & 15;
    const int lrow = lane >> 3;
    const int lsw  = ((lane & 7) ^ lrow) * 8;
    const unsigned short* A0 = F1b + ((size_t)b * 512 + seg * 64) * 384;
    f32x4 acc[2][2];
#pragma unroll
    for (int i = 0; i < 2; i++)
#pragma unroll
        for (int n = 0; n < 2; n++) acc[i][n] = (f32x4){0.f, 0.f, 0.f, 0.f};

    auto stageA = [&](int buf, int s) {       // 2 DMA / wave / tile
        int k0 = s * 64;
#pragma unroll
        for (int j = 0; j < 2; j++) {
            int r0 = wave * 16 + j * 8;
            GLD16(A0 + (size_t)(r0 + lrow) * 384 + k0 + lsw, As + buf * 4096 + r0 * 64);
        }
    };
    stageA(0, 0); stageA(1, 1);
    for (int s = 0; s < 6; s++) {
        const int buf = s & 1;
        if (s + 1 < 6) asm volatile("s_waitcnt vmcnt(2)" ::: "memory");
        else           asm volatile("s_waitcnt vmcnt(0)" ::: "memory");
        __builtin_amdgcn_s_barrier();
        __builtin_amdgcn_sched_barrier(0);
        bf16x8 af[2][2], bfr[2][2];
#pragma unroll
        for (int h = 0; h < 2; h++) {
            int phys = ((h * 4 + quad) ^ (l16 & 7)) * 8;
#pragma unroll
            for (int i = 0; i < 2; i++)
                af[h][i] = *(const bf16x8*)(As + buf * 4096 + (wm * 32 + i * 16 + l16) * 64 + phys);
#pragma unroll
            for (int n = 0; n < 2; n++)
                bfr[h][n] = *(const bf16x8*)(Bs + s * 4096 + (wn * 32 + n * 16 + l16) * 64 + phys);
        }
        asm volatile("s_waitcnt lgkmcnt(0)" ::: "memory");
        __builtin_amdgcn_sched_barrier(0);
        __builtin_amdgcn_s_barrier();
        __builtin_amdgcn_sched_barrier(0);
        if (s + 2 < 6) stageA(buf, s + 2);
#pragma unroll
        for (int h = 0; h < 2; h++)
#pragma unroll
            for (int i = 0; i < 2; i++)
#pragma unroll
                for (int n = 0; n < 2; n++)
                    acc[i][n] = __builtin_amdgcn_mfma_f32_16x16x32_bf16(af[h][i], bfr[h][n], acc[i][n], 0, 0, 0);
    }

    // ---- epilogue: leaky + store + colsum ----
    float ls[2];
#pragma unroll
    for (int n = 0; n < 2; n++) ls[n] = 0.f;
#pragma unroll
    for (int i = 0; i < 2; i++) {
        int nd = seg * 64 + wm * 32 + i * 16 + quad * 4;
#pragma unroll
        for (int n = 0; n < 2; n++) {
            int lcol = wn * 32 + n * 16 + l16;
            int col = nt * 64 + lcol;
            float bb = beffF[lcol];
#pragma unroll
            for (int r = 0; r < 4; r++) {
                float x = acc[i][n][r] + bb;
                float v = LEAKY(x);
                out[(size_t)b * 65664 + (size_t)(nd + r + 1) * 128 + col] = v;
                ls[n] += v;
            }
        }
    }
#pragma unroll
    for (int n = 0; n < 2; n++) atomicAdd(&msS[wn * 32 + n * 16 + l16], ls[n]);
    __syncthreads();
    if (t < 64) atomicAdd(&msum[b * 128 + nt * 64 + t], msS[t]);
    __syncthreads();

    // ---- last-block meandep ----
    if (t == 0) {
        __threadfence();
        unsigned int old = atomicAdd(donecnt, 1u);
        lastFlag = (old == 511u) ? 1u : 0u;
    }
    __syncthreads();
    if (lastFlag) {
        for (int i = t; i < 4096; i += 256) {
            int bb = i >> 7, o = i & 127;
            float dep = depot[bb * 2] * Wd[o] + depot[bb * 2 + 1] * Wd[128 + o] + bd[o];
            out[(size_t)bb * 65664 + o] = dep;
            float ms = atomicAdd(&msum[i], 0.f);   // device-coherent read
            out[2101248 + i] = (ms + dep) * (1.0f / 513.0f);
        }
    }
}

// ---------------- launch ----------------

extern "C" void kernel_launch(void* const* d_in, const int* in_sizes, int n_in,
                              void* d_out, int out_size, void* d_ws, size_t ws_size,
                              hipStream_t stream) {
    const float* loc      = (const float*)d_in[0];
    const float* deadline = (const float*)d_in[1];
    const float* depot    = (const float*)d_in[3];
    const float* W_init   = (const float*)d_in[4];
    const float* b_init   = (const float*)d_in[5];
    const float* W_dep    = (const float*)d_in[6];
    const float* b_dep    = (const float*)d_in[7];
    const float* W_g1     = (const float*)d_in[8];
    const float* b_g1     = (const float*)d_in[9];
    const float* W_g2     = (const float*)d_in[10];
    const float* b_g2     = (const float*)d_in[11];
    const float* W_g3     = (const float*)d_in[12];
    const float* b_g3     = (const float*)d_in[13];
    const float* gamma    = (const float*)d_in[14];
    const float* beta     = (const float*)d_in[15];
    const float* W_F      = (const float*)d_in[16];
    const float* b_F      = (const float*)d_in[17];
    float* out = (float*)d_out;
    float* ws  = (float*)d_ws;

    // workspace (float offsets, 16B aligned); ~93 MB
    float* dmaxv  = ws + 0;         // [0] dmax ; [2] donecnt (uint)
    unsigned int* donecnt = (unsigned int*)(ws + 2);
    float* pmax64 = ws + 4;         // 64
    float* bn1    = ws + 68;        // 384
    float* bn2    = ws + 452;       // 384
    float* msum   = ws + 836;       // 4096
    float* rowsum = ws + 4932;      // 16384
    unsigned short* Lb   = (unsigned short*)(ws + 21448);     // 8388608 u16
    unsigned short* P1   = (unsigned short*)(ws + 4215752);   // 6291456 u16
    unsigned short* P2   = (unsigned short*)(ws + 7361480);
    unsigned short* P3   = (unsigned short*)(ws + 10507208);
    unsigned short* WgT  = (unsigned short*)(ws + 13652936);  // 442368 u16
    unsigned short* Y2T  = (unsigned short*)(ws + 13898696);  // 6291456 u16
    unsigned short* ZT   = (unsigned short*)(ws + 17044424);
    unsigned short* F1b  = (unsigned short*)(ws + 20190152);

    // zero: dmaxv/donecnt, pmax64, bn1, bn2, msum (contiguous low region)
    hipMemsetAsync(ws, 0, 4932 * sizeof(float), stream);

    k_dmax<<<64, 256, 0, stream>>>(deadline, dmaxv);
    k_rowstats<<<4096, 256, 0, stream>>>(loc, deadline, dmaxv, rowsum, pmax64);
    k_build<<<16064, 256, 0, stream>>>(loc, deadline, dmaxv, rowsum, pmax64,
                                       W_init, b_init, W_g1, W_g2, W_g3,
                                       Lb, P1, P2, P3, WgT);

    k_ygemmT<<<384, 256, 0, stream>>>(WgT, P1, P2, P3, Y2T);
    k_lg1T<<<384, 256, 0, stream>>>(Lb, Y2T, WgT, P1, P2, P3, ZT);
    k_lg2<<<384, 256, 0, stream>>>(Lb, ZT, WgT, P1, P2, P3,
                                   b_g1, b_g2, b_g3, F1b, bn1, bn2);

    k_fgemm2<<<512, 256, 0, stream>>>(F1b, bn1, bn2, gamma, beta, W_F, b_F,
                                      depot, W_dep, b_dep, out, msum, donecnt);
}

// Round 10
// 223.233 us; speedup vs baseline: 6.7645x; 1.0771x over previous
//
#include <hip/hip_runtime.h>

#define LEAKY(x) ((x) > 0.0f ? (x) : 0.01f * (x))

typedef __attribute__((ext_vector_type(8))) short bf16x8;      // MFMA A/B frag
typedef __attribute__((ext_vector_type(4))) float f32x4;       // MFMA C/D frag
typedef __attribute__((ext_vector_type(8))) unsigned short u16x8;
typedef __attribute__((ext_vector_type(4))) unsigned short u16x4;

__device__ __forceinline__ unsigned short f2bf(float f) {
    unsigned int u = __float_as_uint(f);
    unsigned int r = (u + 0x7fffu + ((u >> 16) & 1u)) >> 16;   // RNE
    return (unsigned short)r;
}
__device__ __forceinline__ float bf2f(unsigned short u) {
    return __uint_as_float(((unsigned int)u) << 16);
}

// async global->LDS DMA, 16B per lane. LDS dest is WAVE-UNIFORM base + lane*16;
// global src is per-lane (carries the inverse swizzle).
#define GLD16(gp, lp) __builtin_amdgcn_global_load_lds( \
    (__attribute__((address_space(1))) void*)(gp), \
    (__attribute__((address_space(3))) void*)(lp), 16, 0, 0)

// ---------------- small builds ----------------

// wide max via atomicMax (values > 0 so uint ordering == float ordering); grid 64
__global__ void k_dmax(const float* __restrict__ deadline, float* __restrict__ dmax) {
    int t = threadIdx.x;
    float m = deadline[blockIdx.x * 256 + t];
    for (int off = 32; off > 0; off >>= 1) m = fmaxf(m, __shfl_down(m, off));
    __shared__ float s[4];
    if ((t & 63) == 0) s[t >> 6] = m;
    __syncthreads();
    if (t == 0) atomicMax((unsigned int*)dmax,
                          __float_as_uint(fmaxf(fmaxf(s[0], s[1]), fmaxf(s[2], s[3]))));
}

// rowsum + 64-slot atomicMax partials of r=1/dist; R is NOT materialized
__global__ __launch_bounds__(256) void k_rowstats(const float* __restrict__ loc,
                                                  const float* __restrict__ deadline,
                                                  const float* __restrict__ dmaxv,
                                                  float* __restrict__ rowsum, float* __restrict__ pmax64) {
    int blk = blockIdx.x;                       // 0..4095
    int wave = threadIdx.x >> 6, lane = threadIdx.x & 63;
    int bi = blk * 4 + wave;                    // b*512 + i
    int b = bi >> 9, i = bi & 511;
    float invd = 1.0f / (*dmaxv);
    const float* lb = loc + b * 1024;
    const float* db = deadline + b * 512;
    float xi = lb[i * 2], yi = lb[i * 2 + 1], zi = db[i] * invd;
    float lsum = 0.f, lmax = 0.f;
    for (int j = lane; j < 512; j += 64) {
        float d0 = xi - lb[j * 2], d1 = yi - lb[j * 2 + 1], d2 = zi - db[j] * invd;
        float dd = d0 * d0 + d1 * d1 + d2 * d2;
        float r = (j == i) ? 0.f : rsqrtf(dd);
        lsum += r; lmax = fmaxf(lmax, r);
    }
    for (int off = 32; off > 0; off >>= 1) {
        lsum += __shfl_down(lsum, off);
        lmax = fmaxf(lmax, __shfl_down(lmax, off));
    }
    __shared__ float smax[4];
    if (lane == 0) { rowsum[bi] = lsum; smax[wave] = lmax; }
    __syncthreads();
    if (threadIdx.x == 0) {
        float m = fmaxf(fmaxf(smax[0], smax[1]), fmaxf(smax[2], smax[3]));
        atomicMax((unsigned int*)(pmax64 + (blk & 63)), __float_as_uint(m));
    }
}

// fused build: [0,8192) L ; [8192,14336) F0 powers ; [14336,16064) WgT repack
__global__ __launch_bounds__(256) void k_build(
    const float* __restrict__ loc, const float* __restrict__ deadline,
    const float* __restrict__ dmaxv, const float* __restrict__ rowsum,
    const float* __restrict__ pmax64,
    const float* __restrict__ Wi, const float* __restrict__ bi_,
    const float* __restrict__ Wg1, const float* __restrict__ Wg2, const float* __restrict__ Wg3,
    unsigned short* __restrict__ Lb,
    unsigned short* __restrict__ P1, unsigned short* __restrict__ P2, unsigned short* __restrict__ P3,
    unsigned short* __restrict__ WgT)
{
    __shared__ float amaxS;
    int blk = blockIdx.x;
    int t = threadIdx.x;
    if (blk < 8192) {
        // ---- L bf16 (symmetric), recompute r on the fly: 4 j's per thread ----
        if (t < 64) {
            float m = pmax64[t];
            for (int off = 32; off > 0; off >>= 1) m = fmaxf(m, __shfl_down(m, off));
            if (t == 0) amaxS = m;
        }
        __syncthreads();
        float inv = 1.0f / amaxS;
        float invd = 1.0f / (*dmaxv);
        int id = blk * 256 + t;
        size_t e = (size_t)id * 4;
        size_t bi = e >> 9;
        int b = (int)(bi >> 9);
        int i = (int)(bi & 511);
        int j0 = (int)(e & 511);
        const float* lb = loc + b * 1024;
        const float* db = deadline + b * 512;
        float xi = lb[i * 2], yi = lb[i * 2 + 1], zi = db[i] * invd;
        float4 l01 = *(const float4*)(lb + j0 * 2);
        float4 l23 = *(const float4*)(lb + j0 * 2 + 4);
        float4 dj = *(const float4*)(db + j0);
        float diag = rowsum[bi] * inv - 1.0f;
        float jx[4] = {l01.x, l01.z, l23.x, l23.z};
        float jy[4] = {l01.y, l01.w, l23.y, l23.w};
        float jz[4] = {dj.x * invd, dj.y * invd, dj.z * invd, dj.w * invd};
        u16x4 o;
#pragma unroll
        for (int j = 0; j < 4; j++) {
            float d0 = xi - jx[j], d1 = yi - jy[j], d2 = zi - jz[j];
            float dd = d0 * d0 + d1 * d1 + d2 * d2;
            float v = (i == j0 + j) ? diag : -rsqrtf(dd) * inv;
            o[j] = f2bf(v);
        }
        *(u16x4*)(Lb + e) = o;
    } else if (blk < 14336) {
        // ---- F0 powers, bf16 row-major [16384][384] x3, 4 cols per thread ----
        int id = (blk - 8192) * 256 + t;          // 1,572,864
        int row = id / 96, c4 = (id % 96) * 4;
        float x0 = loc[row * 2], x1 = loc[row * 2 + 1], x2 = deadline[row] / (*dmaxv);
        float4 w0 = *(const float4*)(Wi + c4);
        float4 w1 = *(const float4*)(Wi + 384 + c4);
        float4 w2 = *(const float4*)(Wi + 768 + c4);
        float4 bb = *(const float4*)(bi_ + c4);
        float f[4] = {x0 * w0.x + x1 * w1.x + x2 * w2.x + bb.x,
                      x0 * w0.y + x1 * w1.y + x2 * w2.y + bb.y,
                      x0 * w0.z + x1 * w1.z + x2 * w2.z + bb.z,
                      x0 * w0.w + x1 * w1.w + x2 * w2.w + bb.w};
        u16x4 o1, o2, o3;
#pragma unroll
        for (int j = 0; j < 4; j++) {
            o1[j] = f2bf(f[j]); o2[j] = f2bf(f[j] * f[j]); o3[j] = f2bf(f[j] * f[j] * f[j]);
        }
        size_t e = (size_t)row * 384 + c4;
        *(u16x4*)(P1 + e) = o1; *(u16x4*)(P2 + e) = o2; *(u16x4*)(P3 + e) = o3;
    } else {
        // ---- WgT[part][g][k] = Wg{g/128}[(part*384+k)*128 + (g&127)] ----
        int id = (blk - 14336) * 256 + t;         // 442368 exact
        int part = id / 147456, rem = id % 147456;
        int g = rem / 384, k = rem % 384;
        int kp = g >> 7, n = g & 127;
        const float* W = (kp == 0) ? Wg1 : (kp == 1 ? Wg2 : Wg3);
        WgT[id] = f2bf(W[(part * 384 + k) * 128 + n]);
    }
}

// ---------------- pipelined MFMA cores: counted-vmcnt, 2-deep prefetch ----------------
// T4 structure: raw s_barrier + s_waitcnt vmcnt(N) with N = instrs of the NEWEST tile
// still allowed in flight -> loads for tile s+1 stay outstanding ACROSS barriers; tile
// s+2's DMA issues under the MFMAs. vmcnt never drains to 0 in steady state.
// Per iter: vmcnt(W); bar; [frag ds_reads]; lgkmcnt(0); bar; stage(s+2); MFMAs.
// Swizzle (rule #21): LDS dest linear, global SOURCE pre-swizzled per lane with the
// same involution (chunk ^= row&7) the ds_read side uses.
// 128x128 tile: 4 waves 2x2, wave tile 64x64 (4x4 frags), 32 MFMA/wave/iter.

__device__ __forceinline__ void pipe128x128(
    const unsigned short* __restrict__ A0, int As0, const unsigned short* __restrict__ B0, int Bs0, int it0,
    const unsigned short* __restrict__ A1, int As1, const unsigned short* __restrict__ B1, int Bs1, int it1,
    unsigned short* AsL, unsigned short* BsL,   // each 16384 u16 (2 bufs x 8192)
    f32x4 (&acc)[4][4], int t)
{
    const int lane = t & 63, wave = t >> 6;
    const int wm = wave >> 1, wn = wave & 1;
    const int quad = lane >> 4, l16 = lane & 15;
    const int lrow = lane >> 3;                  // 0..7 row within 8-row stripe
    const int lsw  = ((lane & 7) ^ lrow) * 8;    // inverse-swizzled src chunk (u16 units)
    const int total = it0 + it1;

    auto stage = [&](int buf, int s) {           // 8 DMA instr / wave / tile
        int sg = (s >= it0);
        const unsigned short* A = sg ? A1 : A0;
        const unsigned short* B = sg ? B1 : B0;
        int As = sg ? As1 : As0, Bs = sg ? Bs1 : Bs0;
        int k0 = (sg ? (s - it0) : s) * 64;
#pragma unroll
        for (int j = 0; j < 4; j++) {            // 128 rows A + 128 rows B, 8 rows/DMA
            int r0 = wave * 32 + j * 8;
            GLD16(A + (size_t)(r0 + lrow) * As + k0 + lsw, AsL + buf * 8192 + r0 * 64);
            GLD16(B + (size_t)(r0 + lrow) * Bs + k0 + lsw, BsL + buf * 8192 + r0 * 64);
        }
    };

    stage(0, 0);
    if (total > 1) stage(1, 1);
    for (int s = 0; s < total; s++) {
        const int buf = s & 1;
        // tile s landed (8 newest = tile s+1 may stay in flight); extra older strays only over-wait
        if (s + 1 < total) asm volatile("s_waitcnt vmcnt(8)" ::: "memory");
        else               asm volatile("s_waitcnt vmcnt(0)" ::: "memory");
        __builtin_amdgcn_s_barrier();             // ALL waves' tile-s DMA visible
        __builtin_amdgcn_sched_barrier(0);
        bf16x8 af[2][4], bfr[2][4];
#pragma unroll
        for (int h = 0; h < 2; h++) {
            int phys = ((h * 4 + quad) ^ (l16 & 7)) * 8;
#pragma unroll
            for (int i = 0; i < 4; i++)
                af[h][i] = *(const bf16x8*)(AsL + buf * 8192 + (wm * 64 + i * 16 + l16) * 64 + phys);
#pragma unroll
            for (int n = 0; n < 4; n++)
                bfr[h][n] = *(const bf16x8*)(BsL + buf * 8192 + (wn * 64 + n * 16 + l16) * 64 + phys);
        }
        asm volatile("s_waitcnt lgkmcnt(0)" ::: "memory");   // frag reads retired
        __builtin_amdgcn_sched_barrier(0);
        __builtin_amdgcn_s_barrier();             // all waves done READING buf
        __builtin_amdgcn_sched_barrier(0);
        if (s + 2 < total) stage(buf, s + 2);     // refill freed buf under the MFMAs
#pragma unroll
        for (int h = 0; h < 2; h++)
#pragma unroll
            for (int i = 0; i < 4; i++)
#pragma unroll
                for (int n = 0; n < 4; n++)
                    acc[i][n] = __builtin_amdgcn_mfma_f32_16x16x32_bf16(af[h][i], bfr[h][n], acc[i][n], 0, 0, 0);
    }
}

// 64x64 tile: wave tile 32x32 (2x2 frags), 8 MFMA/wave/iter
__device__ __forceinline__ void pipe64x64(
    const unsigned short* __restrict__ A0, int As0, const unsigned short* __restrict__ B0, int Bs0, int it0,
    unsigned short* AsL, unsigned short* BsL,   // 8192 / 8192 u16
    f32x4 (&acc)[2][2], int t)
{
    const int lane = t & 63, wave = t >> 6;
    const int wm = wave >> 1, wn = wave & 1;
    const int quad = lane >> 4, l16 = lane & 15;
    const int lrow = lane >> 3;
    const int lsw  = ((lane & 7) ^ lrow) * 8;

    auto stage = [&](int buf, int s) {           // 4 DMA instr / wave / tile
        int k0 = s * 64;
#pragma unroll
        for (int j = 0; j < 2; j++) {
            int r0 = wave * 16 + j * 8;
            GLD16(A0 + (size_t)(r0 + lrow) * As0 + k0 + lsw, AsL + buf * 4096 + r0 * 64);
            GLD16(B0 + (size_t)(r0 + lrow) * Bs0 + k0 + lsw, BsL + buf * 4096 + r0 * 64);
        }
    };

    stage(0, 0);
    if (it0 > 1) stage(1, 1);
    for (int s = 0; s < it0; s++) {
        const int buf = s & 1;
        if (s + 1 < it0) asm volatile("s_waitcnt vmcnt(4)" ::: "memory");
        else             asm volatile("s_waitcnt vmcnt(0)" ::: "memory");
        __builtin_amdgcn_s_barrier();
        __builtin_amdgcn_sched_barrier(0);
        bf16x8 af[2][2], bfr[2][2];
#pragma unroll
        for (int h = 0; h < 2; h++) {
            int phys = ((h * 4 + quad) ^ (l16 & 7)) * 8;
#pragma unroll
            for (int i = 0; i < 2; i++)
                af[h][i] = *(const bf16x8*)(AsL + buf * 4096 + (wm * 32 + i * 16 + l16) * 64 + phys);
#pragma unroll
            for (int n = 0; n < 2; n++)
                bfr[h][n] = *(const bf16x8*)(BsL + buf * 4096 + (wn * 32 + n * 16 + l16) * 64 + phys);
        }
        asm volatile("s_waitcnt lgkmcnt(0)" ::: "memory");
        __builtin_amdgcn_sched_barrier(0);
        __builtin_amdgcn_s_barrier();
        __builtin_amdgcn_sched_barrier(0);
        if (s + 2 < it0) stage(buf, s + 2);
#pragma unroll
        for (int h = 0; h < 2; h++)
#pragma unroll
            for (int i = 0; i < 2; i++)
#pragma unroll
                for (int n = 0; n < 2; n++)
                    acc[i][n] = __builtin_amdgcn_mfma_f32_16x16x32_bf16(af[h][i], bfr[h][n], acc[i][n], 0, 0, 0);
    }
}

// Y2^T[g][node] = WgT(p2)·P^T ; grid 384, id = b + 32*(kp*4+nb)
__global__ __launch_bounds__(256) void k_ygemmT(
    const unsigned short* __restrict__ WgT,
    const unsigned short* __restrict__ P1, const unsigned short* __restrict__ P2,
    const unsigned short* __restrict__ P3, unsigned short* __restrict__ Y2T)
{
    __shared__ unsigned short AsL[16384], BsL[16384];
    const int t = threadIdx.x;
    const int id = blockIdx.x;
    const int b = id & 31, tt = id >> 5;
    const int kp = tt >> 2, nb = tt & 3;
    const unsigned short* P = (kp == 0) ? P1 : (kp == 1 ? P2 : P3);
    f32x4 acc[4][4];
#pragma unroll
    for (int i = 0; i < 4; i++)
#pragma unroll
        for (int n = 0; n < 4; n++) acc[i][n] = (f32x4){0.f, 0.f, 0.f, 0.f};
    pipe128x128(WgT + ((size_t)2 * 384 + kp * 128) * 384, 384,
                P + ((size_t)b * 512 + nb * 128) * 384, 384, 6,
                nullptr, 0, nullptr, 0, 0, AsL, BsL, acc, t);

    const int wave = t >> 6, lane = t & 63;
    const int wm = wave >> 1, wn = wave & 1;
    const int quad = lane >> 4, l16 = lane & 15;
#pragma unroll
    for (int i = 0; i < 4; i++)
#pragma unroll
        for (int n = 0; n < 4; n++) {
            int g = kp * 128 + wm * 64 + i * 16 + quad * 4;
            int node = nb * 128 + wn * 64 + n * 16 + l16;
#pragma unroll
            for (int r = 0; r < 4; r++)
                Y2T[((size_t)b * 384 + g + r) * 512 + node] = f2bf(acc[i][n][r]);
        }
}

// Z^T = Y2T·L + WgT(p1)·P^T ; grid 384
__global__ __launch_bounds__(256) void k_lg1T(
    const unsigned short* __restrict__ Lb, const unsigned short* __restrict__ Y2T,
    const unsigned short* __restrict__ WgT,
    const unsigned short* __restrict__ P1, const unsigned short* __restrict__ P2,
    const unsigned short* __restrict__ P3, unsigned short* __restrict__ ZT)
{
    __shared__ unsigned short AsL[16384], BsL[16384];
    const int t = threadIdx.x;
    const int id = blockIdx.x;
    const int b = id & 31, tt = id >> 5;
    const int kp = tt >> 2, nb = tt & 3;
    const unsigned short* P = (kp == 0) ? P1 : (kp == 1 ? P2 : P3);
    f32x4 acc[4][4];
#pragma unroll
    for (int i = 0; i < 4; i++)
#pragma unroll
        for (int n = 0; n < 4; n++) acc[i][n] = (f32x4){0.f, 0.f, 0.f, 0.f};
    pipe128x128(Y2T + (size_t)b * 196608 + (size_t)kp * 128 * 512, 512,
                Lb + (size_t)b * 262144 + (size_t)nb * 128 * 512, 512, 8,
                WgT + ((size_t)1 * 384 + kp * 128) * 384, 384,
                P + ((size_t)b * 512 + nb * 128) * 384, 384, 6, AsL, BsL, acc, t);

    const int wave = t >> 6, lane = t & 63;
    const int wm = wave >> 1, wn = wave & 1;
    const int quad = lane >> 4, l16 = lane & 15;
#pragma unroll
    for (int i = 0; i < 4; i++)
#pragma unroll
        for (int n = 0; n < 4; n++) {
            int g = kp * 128 + wm * 64 + i * 16 + quad * 4;
            int node = nb * 128 + wn * 64 + n * 16 + l16;
#pragma unroll
            for (int r = 0; r < 4; r++)
                ZT[((size_t)b * 384 + g + r) * 512 + node] = f2bf(acc[i][n][r]);
        }
}

// F1 = leaky(L·Z + P·WgT(p0)^T + bias) + F0 ; fused BN sums ; grid 384, tt = gt*4+mb
__global__ __launch_bounds__(256) void k_lg2(
    const unsigned short* __restrict__ Lb, const unsigned short* __restrict__ ZT,
    const unsigned short* __restrict__ WgT,
    const unsigned short* __restrict__ P1, const unsigned short* __restrict__ P2,
    const unsigned short* __restrict__ P3,
    const float* __restrict__ bg1, const float* __restrict__ bg2, const float* __restrict__ bg3,
    unsigned short* __restrict__ F1b, float* __restrict__ bn1, float* __restrict__ bn2)
{
    __shared__ unsigned short AsL[16384], BsL[16384];
    __shared__ float bnS[128], bnQ[128];
    const int t = threadIdx.x;
    const int id = blockIdx.x;
    const int b = id & 31, tt = id >> 5;
    const int mb = tt & 3, gt = tt >> 2;          // mb: node tile(128), gt=kp: gcol tile(128) 0..2
    if (t < 128) { bnS[t] = 0.f; bnQ[t] = 0.f; }  // pipe's first barrier covers this
    const unsigned short* P = (gt == 0) ? P1 : (gt == 1 ? P2 : P3);
    f32x4 acc[4][4];
#pragma unroll
    for (int i = 0; i < 4; i++)
#pragma unroll
        for (int n = 0; n < 4; n++) acc[i][n] = (f32x4){0.f, 0.f, 0.f, 0.f};
    pipe128x128(Lb + (size_t)b * 262144 + (size_t)mb * 128 * 512, 512,
                ZT + (size_t)b * 196608 + (size_t)gt * 128 * 512, 512, 8,
                P + ((size_t)b * 512 + mb * 128) * 384, 384,
                WgT + (size_t)(gt * 128) * 384, 384, 6,
                AsL, BsL, acc, t);

    const int wave = t >> 6, lane = t & 63;
    const int wm = wave >> 1, wn = wave & 1;
    const int quad = lane >> 4, l16 = lane & 15;
    const float* bg = (gt == 0) ? bg1 : (gt == 1 ? bg2 : bg3);
    float ls1[4], ls2[4];
#pragma unroll
    for (int n = 0; n < 4; n++) { ls1[n] = 0.f; ls2[n] = 0.f; }
#pragma unroll
    for (int i = 0; i < 4; i++) {
        int rowl = mb * 128 + wm * 64 + i * 16 + quad * 4;
        size_t rowg = (size_t)b * 512 + rowl;
#pragma unroll
        for (int n = 0; n < 4; n++) {
            int nloc = wn * 64 + n * 16 + l16;    // 0..127
            int g = gt * 128 + nloc;
            float bias = bg[nloc];
#pragma unroll
            for (int r = 0; r < 4; r++) {
                size_t idx = (rowg + r) * 384 + g;
                float c = acc[i][n][r] + bias;
                float v = LEAKY(c) + bf2f(P1[idx]);   // residual +F0
                F1b[idx] = f2bf(v);
                ls1[n] += v; ls2[n] += v * v;
            }
        }
    }
#pragma unroll
    for (int n = 0; n < 4; n++) {
        int nloc = wn * 64 + n * 16 + l16;
        atomicAdd(&bnS[nloc], ls1[n]);
        atomicAdd(&bnQ[nloc], ls2[n]);
    }
    __syncthreads();
    if (t < 128) {
        atomicAdd(&bn1[gt * 128 + t], bnS[t]);
        atomicAdd(&bn2[gt * 128 + t], bnQ[t]);
    }
}

// merged: BN finish + fold scale into W_F^T (blocks 0..191) + effective bias (block 192)
__global__ __launch_bounds__(256) void k_bnfold(
    const float* __restrict__ bn1, const float* __restrict__ bn2,
    const float* __restrict__ gamma, const float* __restrict__ beta,
    const float* __restrict__ WF, const float* __restrict__ bF,
    unsigned short* __restrict__ WFsT, float* __restrict__ beffv)
{
    int blk = blockIdx.x;
    if (blk < 192) {                              // WFsT[n][k] = W_F[k][n]*sc[k]
        int id = blk * 256 + threadIdx.x;         // 49152
        int n = id / 384, k = id % 384;
        float mu = bn1[k] * (1.f / 16384.f);
        float var = bn2[k] * (1.f / 16384.f) - mu * mu;
        float sc = gamma[k] / sqrtf(var + 1e-5f);
        WFsT[id] = f2bf(WF[k * 128 + n] * sc);
    } else {                                      // beff[c] = bF[c] + sum_k ttL[k]*WF[k][c]
        __shared__ float ttL[384];
        int c = threadIdx.x;
        for (int k = c; k < 384; k += 256) {
            float mu = bn1[k] * (1.f / 16384.f);
            float var = bn2[k] * (1.f / 16384.f) - mu * mu;
            float sc = gamma[k] / sqrtf(var + 1e-5f);
            ttL[k] = beta[k] - mu * sc;
        }
        __syncthreads();
        if (c < 128) {
            float a = bF[c];
            for (int k = 0; k < 384; k++) a += ttL[k] * WF[k * 128 + c];
            beffv[c] = a;
        }
    }
}

// out rows 1..512 = leaky(F1b @ WFsT + beff); fused column-sum partials
// 1D grid 512: id = b + 32*(seg*2+nt)
__global__ __launch_bounds__(256) void k_fgemm(
    const unsigned short* __restrict__ F1b, const unsigned short* __restrict__ WFsT,
    const float* __restrict__ beffv, float* __restrict__ out, float* __restrict__ msum)
{
    __shared__ unsigned short AsL[8192], BsL[8192];
    __shared__ float msS[64];
    const int t = threadIdx.x;
    const int id = blockIdx.x;
    const int b = id & 31, tt = id >> 5;
    const int seg = tt >> 1, nt = tt & 1;
    if (t < 64) msS[t] = 0.f;                     // pipe's first barrier covers this
    f32x4 acc[2][2];
#pragma unroll
    for (int i = 0; i < 2; i++)
#pragma unroll
        for (int n = 0; n < 2; n++) acc[i][n] = (f32x4){0.f, 0.f, 0.f, 0.f};
    pipe64x64(F1b + ((size_t)b * 512 + seg * 64) * 384, 384,
              WFsT + (size_t)nt * 64 * 384, 384, 6, AsL, BsL, acc, t);

    const int wave = t >> 6, lane = t & 63;
    const int wm = wave >> 1, wn = wave & 1;
    const int quad = lane >> 4, l16 = lane & 15;
    float ls[2];
#pragma unroll
    for (int n = 0; n < 2; n++) ls[n] = 0.f;
#pragma unroll
    for (int i = 0; i < 2; i++) {
        int nd = seg * 64 + wm * 32 + i * 16 + quad * 4;
#pragma unroll
        for (int n = 0; n < 2; n++) {
            int col = nt * 64 + wn * 32 + n * 16 + l16;
            float bb = beffv[col];
#pragma unroll
            for (int r = 0; r < 4; r++) {
                float x = acc[i][n][r] + bb;
                float v = LEAKY(x);
                out[(size_t)b * 65664 + (size_t)(nd + r + 1) * 128 + col] = v;
                ls[n] += v;
            }
        }
    }
#pragma unroll
    for (int n = 0; n < 2; n++) atomicAdd(&msS[wn * 32 + n * 16 + l16], ls[n]);
    __syncthreads();
    if (t < 64) atomicAdd(&msum[b * 128 + nt * 64 + t], msS[t]);
}

// depot row + final means
__global__ void k_meandep(const float* __restrict__ depot, const float* __restrict__ Wd,
                          const float* __restrict__ bd, const float* __restrict__ msum,
                          float* __restrict__ out) {
    int id = blockIdx.x * 256 + threadIdx.x;   // 4096
    int b = id >> 7, o = id & 127;
    float dep = depot[b * 2] * Wd[o] + depot[b * 2 + 1] * Wd[128 + o] + bd[o];
    out[(size_t)b * 65664 + o] = dep;
    out[2101248 + id] = (msum[id] + dep) * (1.0f / 513.0f);
}

// ---------------- launch ----------------

extern "C" void kernel_launch(void* const* d_in, const int* in_sizes, int n_in,
                              void* d_out, int out_size, void* d_ws, size_t ws_size,
                              hipStream_t stream) {
    const float* loc      = (const float*)d_in[0];
    const float* deadline = (const float*)d_in[1];
    const float* depot    = (const float*)d_in[3];
    const float* W_init   = (const float*)d_in[4];
    const float* b_init   = (const float*)d_in[5];
    const float* W_dep    = (const float*)d_in[6];
    const float* b_dep    = (const float*)d_in[7];
    const float* W_g1     = (const float*)d_in[8];
    const float* b_g1     = (const float*)d_in[9];
    const float* W_g2     = (const float*)d_in[10];
    const float* b_g2     = (const float*)d_in[11];
    const float* W_g3     = (const float*)d_in[12];
    const float* b_g3     = (const float*)d_in[13];
    const float* gamma    = (const float*)d_in[14];
    const float* beta     = (const float*)d_in[15];
    const float* W_F      = (const float*)d_in[16];
    const float* b_F      = (const float*)d_in[17];
    float* out = (float*)d_out;
    float* ws  = (float*)d_ws;

    // workspace (float offsets, 16B aligned); ~93 MB
    float* dmaxv  = ws + 0;         // 4
    float* pmax64 = ws + 4;         // 64
    float* bn1    = ws + 68;        // 384
    float* bn2    = ws + 452;       // 384
    float* msum   = ws + 836;       // 4096
    float* rowsum = ws + 4932;      // 16384
    float* beffv  = ws + 21316;     // 128 (+4 pad)
    unsigned short* Lb   = (unsigned short*)(ws + 21448);     // 8388608 u16
    unsigned short* P1   = (unsigned short*)(ws + 4215752);   // 6291456 u16
    unsigned short* P2   = (unsigned short*)(ws + 7361480);
    unsigned short* P3   = (unsigned short*)(ws + 10507208);
    unsigned short* WgT  = (unsigned short*)(ws + 13652936);  // 442368 u16
    unsigned short* WFsT = (unsigned short*)(ws + 13874120);  // 49152 u16
    unsigned short* Y2T  = (unsigned short*)(ws + 13898696);  // 6291456 u16
    unsigned short* ZT   = (unsigned short*)(ws + 17044424);
    unsigned short* F1b  = (unsigned short*)(ws + 20190152);

    // zero: dmaxv, pmax64, bn1, bn2, msum  (contiguous low region)
    hipMemsetAsync(ws, 0, 4932 * sizeof(float), stream);

    k_dmax<<<64, 256, 0, stream>>>(deadline, dmaxv);
    k_rowstats<<<4096, 256, 0, stream>>>(loc, deadline, dmaxv, rowsum, pmax64);
    k_build<<<16064, 256, 0, stream>>>(loc, deadline, dmaxv, rowsum, pmax64,
                                       W_init, b_init, W_g1, W_g2, W_g3,
                                       Lb, P1, P2, P3, WgT);

    k_ygemmT<<<384, 256, 0, stream>>>(WgT, P1, P2, P3, Y2T);
    k_lg1T<<<384, 256, 0, stream>>>(Lb, Y2T, WgT, P1, P2, P3, ZT);
    k_lg2<<<384, 256, 0, stream>>>(Lb, ZT, WgT, P1, P2, P3,
                                   b_g1, b_g2, b_g3, F1b, bn1, bn2);

    k_bnfold<<<193, 256, 0, stream>>>(bn1, bn2, gamma, beta, W_F, b_F, WFsT, beffv);
    k_fgemm<<<512, 256, 0, stream>>>(F1b, WFsT, beffv, out, msum);
    k_meandep<<<16, 256, 0, stream>>>(depot, W_dep, b_dep, msum, out);
}